// Round 1
// baseline (370.836 us; speedup 1.0000x reference)
//
#include <hip/hip_runtime.h>
#include <hip/hip_bf16.h>
#include <math.h>

#define EPS 1e-6f

constexpr int D  = 512;
constexpr int BM = 256;
constexpr int BN = 256;

typedef __attribute__((ext_vector_type(8))) short  short8;
typedef __attribute__((ext_vector_type(4))) float  floatx4;

__device__ inline unsigned short f2bf(float f) {
  union { __hip_bfloat16 h; unsigned short u; } cvt;
  cvt.h = __float2bfloat16(f);
  return cvt.u;
}

// ---------------- prep: fp32 -> bf16 + per-row ||x||^(-1/2) ----------------
__global__ __launch_bounds__(256) void prep_kernel(
    const float* __restrict__ src, __hip_bfloat16* __restrict__ dst,
    float* __restrict__ isn, int nrows) {
  const int lane = threadIdx.x & 63;
  const int row  = blockIdx.x * 4 + (threadIdx.x >> 6);
  if (row >= nrows) return;

  const float4* p4 = (const float4*)(src + (size_t)row * D);
  const float4 v1 = p4[lane];
  const float4 v2 = p4[lane + 64];

  if (dst != nullptr) {
    ushort4 u1, u2;
    u1.x = f2bf(v1.x); u1.y = f2bf(v1.y); u1.z = f2bf(v1.z); u1.w = f2bf(v1.w);
    u2.x = f2bf(v2.x); u2.y = f2bf(v2.y); u2.z = f2bf(v2.z); u2.w = f2bf(v2.w);
    ushort4* drow = (ushort4*)(dst + (size_t)row * D);
    drow[lane]      = u1;
    drow[lane + 64] = u2;
  }

  float ss = v1.x * v1.x + v1.y * v1.y + v1.z * v1.z + v1.w * v1.w
           + v2.x * v2.x + v2.y * v2.y + v2.z * v2.z + v2.w * v2.w;
  #pragma unroll
  for (int o = 32; o > 0; o >>= 1) ss += __shfl_down(ss, o);
  if (lane == 0) {
    const float n1 = sqrtf(ss);          // ||row||
    isn[row] = 1.0f / sqrtf(n1);         // ||row||^(-1/2)
  }
}

// ---------------- 256x256 deep-pipelined bf16 MFMA GEMM, C = A * B^T -------
// 8 waves (2Mx4N), BK=64, double-buffered 128 KiB LDS, XOR-swizzled (T2),
// counted vmcnt (T3/T4), setprio around MFMA clusters (T5), XCD swizzle (T1).
// Schedule per K-tile (4 phases):
//   p1: ds-read A[m0-3]+B[n0-1] | bar | lgkm0 | 16 MFMA | bar
//   p2: ds-read B[n2-3]         | bar | lgkm0 | 16 MFMA | bar
//   p3: ds-read A[m4-7]         | bar | lgkm0 | 16 MFMA | bar   <- buffer fully read
//   p4: stage next K-tile into THIS buffer (safe: after p3's barrier)
//       | bar | 16 MFMA | vmcnt(8) | bar
// vmcnt(8) leaves the just-issued K-tile (8 loads) in flight while
// guaranteeing the previously staged K-tile (other buffer) has landed.

#define GLD(srcp, ldsoff_shorts)                                              \
  __builtin_amdgcn_global_load_lds(                                           \
      (const __attribute__((address_space(1))) void*)(srcp),                  \
      (__attribute__((address_space(3))) void*)(smem + (ldsoff_shorts)),      \
      16, 0, 0)

#define STAGE_HALF(gbase, lbase)                                              \
  do {                                                                        \
    GLD((gbase) + soff,                   (lbase) + t * 8);                   \
    GLD((gbase) + soff + (size_t)64 * D,  (lbase) + (t + 512) * 8);           \
  } while (0)

#define STAGE_KTILE(kt, b)                                                    \
  do {                                                                        \
    STAGE_HALF(gA + (kt) * 64,                   ((b) * 2 + 0) * 8192);       \
    STAGE_HALF(gA + (kt) * 64 + (size_t)128 * D, ((b) * 2 + 1) * 8192);       \
    STAGE_HALF(gB + (kt) * 64,                   32768 + ((b) * 2 + 0) * 8192); \
    STAGE_HALF(gB + (kt) * 64 + (size_t)128 * D, 32768 + ((b) * 2 + 1) * 8192); \
  } while (0)

#define RD(p, m, off) (*(const short8*)((p) + (m) * 2048 + rbyte + (off)))

#define MM2(mi, ni)                                                           \
  do {                                                                        \
    acc[mi][ni] = __builtin_amdgcn_mfma_f32_16x16x32_bf16(                    \
        aR[(mi) & 3][0], bR[ni][0], acc[mi][ni], 0, 0, 0);                    \
    acc[mi][ni] = __builtin_amdgcn_mfma_f32_16x16x32_bf16(                    \
        aR[(mi) & 3][1], bR[ni][1], acc[mi][ni], 0, 0, 0);                    \
  } while (0)

#define BAR   __builtin_amdgcn_s_barrier()
#define LGKM0 do { asm volatile("s_waitcnt lgkmcnt(0)" ::: "memory");         \
                   __builtin_amdgcn_sched_barrier(0); } while (0)
#define VM8   asm volatile("s_waitcnt vmcnt(8)" ::: "memory")
#define VM0   asm volatile("s_waitcnt vmcnt(0)" ::: "memory")
#define NOOP  do {} while (0)

#define KTILE(b, STAGE_STMT, WAITV)                                           \
  do {                                                                        \
    const char* pA_ = (const char*)smem + ((b) * 2 + wm) * 16384;             \
    const char* pB_ = (const char*)smem + 65536                               \
                      + ((b) * 2 + (wn >> 1)) * 16384 + (wn & 1) * 8192;      \
    /* p1: A m0-3 (8 reads) + B n0-1 (4 reads) */                             \
    aR[0][0] = RD(pA_, 0, off0); aR[0][1] = RD(pA_, 0, off1);                 \
    aR[1][0] = RD(pA_, 1, off0); aR[1][1] = RD(pA_, 1, off1);                 \
    aR[2][0] = RD(pA_, 2, off0); aR[2][1] = RD(pA_, 2, off1);                 \
    aR[3][0] = RD(pA_, 3, off0); aR[3][1] = RD(pA_, 3, off1);                 \
    bR[0][0] = RD(pB_, 0, off0); bR[0][1] = RD(pB_, 0, off1);                 \
    bR[1][0] = RD(pB_, 1, off0); bR[1][1] = RD(pB_, 1, off1);                 \
    BAR; LGKM0;                                                               \
    __builtin_amdgcn_s_setprio(1);                                            \
    MM2(0,0); MM2(1,0); MM2(2,0); MM2(3,0);                                   \
    MM2(0,1); MM2(1,1); MM2(2,1); MM2(3,1);                                   \
    __builtin_amdgcn_s_setprio(0);                                            \
    BAR;                                                                      \
    /* p2: B n2-3 */                                                          \
    bR[2][0] = RD(pB_, 2, off0); bR[2][1] = RD(pB_, 2, off1);                 \
    bR[3][0] = RD(pB_, 3, off0); bR[3][1] = RD(pB_, 3, off1);                 \
    BAR; LGKM0;                                                               \
    __builtin_amdgcn_s_setprio(1);                                            \
    MM2(0,2); MM2(1,2); MM2(2,2); MM2(3,2);                                   \
    MM2(0,3); MM2(1,3); MM2(2,3); MM2(3,3);                                   \
    __builtin_amdgcn_s_setprio(0);                                            \
    BAR;                                                                      \
    /* p3: A m4-7 (overwrite aR) */                                           \
    aR[0][0] = RD(pA_, 4, off0); aR[0][1] = RD(pA_, 4, off1);                 \
    aR[1][0] = RD(pA_, 5, off0); aR[1][1] = RD(pA_, 5, off1);                 \
    aR[2][0] = RD(pA_, 6, off0); aR[2][1] = RD(pA_, 6, off1);                 \
    aR[3][0] = RD(pA_, 7, off0); aR[3][1] = RD(pA_, 7, off1);                 \
    BAR; LGKM0;                                                               \
    __builtin_amdgcn_s_setprio(1);                                            \
    MM2(4,2); MM2(5,2); MM2(6,2); MM2(7,2);                                   \
    MM2(4,3); MM2(5,3); MM2(6,3); MM2(7,3);                                   \
    __builtin_amdgcn_s_setprio(0);                                            \
    BAR;                                                                      \
    /* p4: stage next K-tile into this buffer (all reads of it are done) */   \
    STAGE_STMT;                                                               \
    BAR;                                                                      \
    __builtin_amdgcn_s_setprio(1);                                            \
    MM2(4,0); MM2(5,0); MM2(6,0); MM2(7,0);                                   \
    MM2(4,1); MM2(5,1); MM2(6,1); MM2(7,1);                                   \
    __builtin_amdgcn_s_setprio(0);                                            \
    WAITV;                                                                    \
    BAR;                                                                      \
  } while (0)

__global__ __launch_bounds__(512, 2) void gemm256_kernel(
    const __hip_bfloat16* __restrict__ A, const __hip_bfloat16* __restrict__ B,
    const float* __restrict__ ia, const float* __restrict__ ib,
    const int* __restrict__ nrmflag, float* __restrict__ C,
    int N, int M) {
  // [ A: buf0{h0,h1} buf1{h0,h1} | B: buf0{h0,h1} buf1{h0,h1} ]  128 KiB
  __shared__ __align__(128) short smem[65536];

  const int t    = threadIdx.x;            // 0..511
  const int lane = t & 63;
  const int w    = t >> 6;                 // 0..7
  const int wm   = w >> 2;                 // 0..1  (M half)
  const int wn   = w & 3;                  // 0..3  (N quarter)

  // T1: XCD-aware chunked swizzle (bijective when nwg % 8 == 0)
  int bid = blockIdx.y * gridDim.x + blockIdx.x;
  const int nwg = (int)(gridDim.x * gridDim.y);
  if ((nwg & 7) == 0) bid = (bid & 7) * (nwg >> 3) + (bid >> 3);
  const int ix = bid % (int)gridDim.x;
  const int iy = bid / (int)gridDim.x;
  const size_t rowA0 = (size_t)ix * BM;
  const size_t rowB0 = (size_t)iy * BN;

  // staging geometry: LDS dest is LINEAR (idx*16B); global SOURCE is
  // pre-swizzled with the same involution the reads use (rule #21).
  const int srow  = t >> 3;                       // 0..63
  const int sslot = (t & 7) ^ (srow & 7);         // swizzled 16B slot
  const size_t soff = (size_t)srow * D + sslot * 8;
  const unsigned short* gA = (const unsigned short*)A + rowA0 * D;
  const unsigned short* gB = (const unsigned short*)B + rowB0 * D;

  // fragment-read geometry (16x16x32): A[m=lane&15][k=(lane>>4)*8+j]
  const int fr    = lane & 15;
  const int g4    = lane >> 4;
  const int rbyte = fr * 128;                     // row stride 128 B (BK=64 bf16)
  const int off0  = ((g4    ) ^ (fr & 7)) * 16;   // ks=0 slot, swizzled
  const int off1  = ((g4 + 4) ^ (fr & 7)) * 16;   // ks=1 slot, swizzled

  floatx4 acc[8][4];
  #pragma unroll
  for (int i = 0; i < 8; ++i)
    #pragma unroll
    for (int j = 0; j < 4; ++j) acc[i][j] = (floatx4){0.f, 0.f, 0.f, 0.f};

  short8 aR[4][2], bR[4][2];

  // prologue: K-tiles 0 and 1; wait for kt0, leave kt1 in flight
  STAGE_KTILE(0, 0);
  STAGE_KTILE(1, 1);
  VM8;
  BAR;

  // main loop: D/64 = 8 K-tiles, 2 per iteration
  #pragma unroll
  for (int it = 0; it < 4; ++it) {
    if (it < 3) {
      KTILE(0, STAGE_KTILE(it * 2 + 2, 0), VM8);
      KTILE(1, STAGE_KTILE(it * 2 + 3, 1), VM8);
    } else {
      KTILE(0, NOOP, VM0);   // drain: guarantee kt7 landed before its reads
      KTILE(1, NOOP, NOOP);
    }
  }

  // epilogue: C/D layout col=lane&15 (B/N index), row=(lane>>4)*4+reg (A/M)
  const int nrm = *nrmflag;
  const int cq  = lane >> 4;   // 0..3
  const int cc  = lane & 15;

  float ibv[4];
  #pragma unroll
  for (int n = 0; n < 4; ++n)
    ibv[n] = nrm ? ib[rowB0 + wn * 64 + n * 16 + cc] : 1.0f;

  #pragma unroll
  for (int m = 0; m < 8; ++m) {
    const size_t rbase = rowA0 + wm * 128 + m * 16 + cq * 4;
    float4 iav4 = nrm ? *(const float4*)(ia + rbase) : (float4){1.f, 1.f, 1.f, 1.f};
    const float iavr[4] = {iav4.x, iav4.y, iav4.z, iav4.w};
    #pragma unroll
    for (int r = 0; r < 4; ++r) {
      float* crow = C + (rbase + r) * (size_t)M + rowB0 + wn * 64 + cc;
      #pragma unroll
      for (int n = 0; n < 4; ++n)
        crow[n * 16] = acc[m][n][r] * iavr[r] * ibv[n];
    }
  }
}

// ---------------- correctness fallback (fp32, used only if ws too small / odd shape)
__global__ __launch_bounds__(256) void fb_gemm(
    const float* __restrict__ A, const float* __restrict__ B,
    const float* __restrict__ ia, const float* __restrict__ ib,
    const int* __restrict__ nrmflag, float* __restrict__ C, int N, int M) {
  __shared__ float sA[32][33];
  __shared__ float sB[32][33];
  const int tx = threadIdx.x & 31;
  const int ty = threadIdx.x >> 5;   // 0..7
  const size_t row0 = (size_t)blockIdx.y * 32;
  const size_t col0 = (size_t)blockIdx.x * 32;
  float acc[4] = {0.f, 0.f, 0.f, 0.f};
  for (int k0 = 0; k0 < D; k0 += 32) {
    #pragma unroll
    for (int r = 0; r < 4; ++r) {
      sA[ty + 8 * r][tx] = A[(row0 + ty + 8 * r) * D + k0 + tx];
      sB[ty + 8 * r][tx] = B[(col0 + ty + 8 * r) * D + k0 + tx];
    }
    __syncthreads();
    #pragma unroll 8
    for (int kk = 0; kk < 32; ++kk) {
      const float bv = sB[tx][kk];
      #pragma unroll
      for (int r = 0; r < 4; ++r) acc[r] += sA[ty + 8 * r][kk] * bv;
    }
    __syncthreads();
  }
  const int nrm  = *nrmflag;
  const float iv = ib[col0 + tx];
  #pragma unroll
  for (int r = 0; r < 4; ++r) {
    const size_t row = row0 + ty + 8 * r;
    float v = acc[r];
    if (nrm) {
      const float denom = 1.0f / (ia[row] * iv) + EPS;  // sqrt(n1*n2)+eps
      v /= denom;
    }
    C[row * (size_t)M + col0 + tx] = v;
  }
}

extern "C" void kernel_launch(void* const* d_in, const int* in_sizes, int n_in,
                              void* d_out, int out_size, void* d_ws, size_t ws_size,
                              hipStream_t stream) {
  const float* A   = (const float*)d_in[0];
  const float* B   = (const float*)d_in[1];
  const int*   nrm = (const int*)d_in[2];
  float*       C   = (float*)d_out;
  const int N = in_sizes[0] / D;
  const int M = in_sizes[1] / D;

  // workspace layout: [ iaN (N f32) | ibN (M f32) | A_bf16 (N*D) | B_bf16 (M*D) ]
  float* iaN = (float*)d_ws;
  float* ibN = iaN + N;
  __hip_bfloat16* Abf = (__hip_bfloat16*)(ibN + M);
  __hip_bfloat16* Bbf = Abf + (size_t)N * D;

  const size_t need = (size_t)(N + M) * sizeof(float)
                    + (size_t)(N + M) * D * sizeof(__hip_bfloat16);
  const bool fast = (ws_size >= need) && (N % BM == 0) && (M % BN == 0);

  prep_kernel<<<(N + 3) / 4, 256, 0, stream>>>(A, fast ? Abf : nullptr, iaN, N);
  prep_kernel<<<(M + 3) / 4, 256, 0, stream>>>(B, fast ? Bbf : nullptr, ibN, M);

  if (fast) {
    gemm256_kernel<<<dim3(N / BM, M / BN), 512, 0, stream>>>(Abf, Bbf, iaN, ibN, nrm, C, N, M);
  } else {
    fb_gemm<<<dim3(M / 32, N / 32), 256, 0, stream>>>(A, B, iaN, ibN, nrm, C, N, M);
  }
}